// Round 10
// baseline (1375.835 us; speedup 1.0000x reference)
//
#include <hip/hip_runtime.h>
#include <hip/hip_bf16.h>

#define N_ATOMS 25000
#define N_PAIRS 500000
#define DEPTH 4
#define APB 49   // atoms per block: pairs/block ~Poisson(980), sigma ~31

typedef _Float16 f16x8 __attribute__((ext_vector_type(8)));
typedef float f32x16 __attribute__((ext_vector_type(16)));

__device__ __forceinline__ float tanh_fast(float x) {
    float e = __expf(2.0f * x);
    return 1.0f - 2.0f * __builtin_amdgcn_rcpf(e + 1.0f);
}

// ---------------- counting sort of pairs by ind_i (ind2 is a fixed input)
__global__ __launch_bounds__(256)
void hist_kernel(const int* __restrict__ ind2, int* __restrict__ hist) {
    int p = blockIdx.x * 256 + threadIdx.x;
    if (p < N_PAIRS) atomicAdd(&hist[ind2[2 * p]], 1);
}

__global__ __launch_bounds__(1024)
void scan_kernel(const int* __restrict__ hist, int* __restrict__ offs) {
    __shared__ int sdata[1024];
    __shared__ int sbase;
    int tid = threadIdx.x;
    if (tid == 0) sbase = 0;
    __syncthreads();
    for (int c = 0; c < N_ATOMS; c += 1024) {
        int v = (c + tid < N_ATOMS) ? hist[c + tid] : 0;
        sdata[tid] = v;
        __syncthreads();
        for (int off = 1; off < 1024; off <<= 1) {
            int t = (tid >= off) ? sdata[tid - off] : 0;
            __syncthreads();
            sdata[tid] += t;
            __syncthreads();
        }
        if (c + tid < N_ATOMS) offs[c + tid] = sbase + sdata[tid] - v;
        __syncthreads();
        if (tid == 1023) sbase += sdata[1023];
        __syncthreads();
    }
}

__global__ __launch_bounds__(256)
void scatter_kernel(const int* __restrict__ ind2, const float* __restrict__ basis,
                    int* __restrict__ offs, int* __restrict__ ind2s,
                    float* __restrict__ basisp) {
    int p = blockIdx.x * 256 + threadIdx.x;
    if (p < N_PAIRS) {
        int i = ind2[2 * p], j = ind2[2 * p + 1];
        int pos = atomicAdd(&offs[i], 1);
        ind2s[2 * pos] = i;
        ind2s[2 * pos + 1] = j;
        ((float4*)basisp)[pos] = ((const float4*)basis)[p];
    }
}
// post-scatter: offs[a] == end offset of atom a == start of atom a+1

// ---------------- prep: fp16 fragment-major weight images
__global__ __launch_bounds__(256)
void prep_kernel(const float* __restrict__ piW1, const float* __restrict__ piW2,
                 const float* __restrict__ iiW1, const float* __restrict__ iiW2,
                 _Float16* __restrict__ img1, _Float16* __restrict__ img2,
                 _Float16* __restrict__ imgab) {
    int gid = blockIdx.x * 256 + threadIdx.x;
    int d = gid >> 15, e = gid & 32767;
    if (e < 8192) {
        int k = e >> 6, n = e & 63;
        int ntw = n >> 5, colb = n & 31;
        int ks = k >> 4, lh = (k >> 3) & 1, j = k & 7;
        img1[d * 8192 + ((ntw * 8 + ks) * 64 + lh * 32 + colb) * 8 + j] =
            (_Float16)piW1[d * 8192 + e];
    } else if (e < 24576) {
        int s = e - 8192;
        int k = s >> 8, n = s & 255;
        int ch = n >> 2, t = n & 3;
        int ntw = ch >> 5, colb = ch & 31;
        int ks = k >> 4, lh = (k >> 3) & 1, j = k & 7;
        img2[d * 16384 + (((ntw * 4 + t) * 4 + ks) * 64 + lh * 32 + colb) * 8 + j] =
            (_Float16)piW2[d * 16384 + s];
    } else {
        int ep = e - 24576;
        int stage = ep >> 12, s = ep & 4095;
        int k = s >> 6, n = s & 63;
        float x = stage ? iiW2[d * 4096 + s] : iiW1[d * 4096 + s];
        int ntw = n >> 5, colb = n & 31;
        int ks = k >> 4, lh = (k >> 3) & 1, j = k & 7;
        imgab[d * 8192 + stage * 4096 + ((ntw * 4 + ks) * 64 + lh * 32 + colb) * 8 + j] =
            (_Float16)x;
    }
}

__global__ __launch_bounds__(256)
void prep_b2(const float* __restrict__ piB2, float* __restrict__ b2p) {
    int d = blockIdx.x, n = threadIdx.x;
    int ch = n >> 2, t = n & 3;
    int np = (ch >> 5) * 128 + t * 32 + (ch & 31);
    b2p[d * 256 + np] = piB2[d * 256 + n];
}

// ---------------- depth-0 atom MLP
__global__ __launch_bounds__(256)
void atom_mlp0(const float* __restrict__ p_in,
               const float* __restrict__ W1, const float* __restrict__ b1,
               const float* __restrict__ W2, const float* __restrict__ b2,
               const float* __restrict__ res0_w,
               _Float16* __restrict__ h_out, float* __restrict__ acc_out) {
    __shared__ float sP[4][16];
    __shared__ float sH[4][64];
    int tid = threadIdx.x;
    int al = tid >> 6, c = tid & 63;
    int a = blockIdx.x * 4 + al;
    if (c < 16) sP[al][c] = p_in[a * 16 + c];
    __syncthreads();
    float s = b1[c], r = 0.f;
#pragma unroll
    for (int k = 0; k < 16; ++k) {
        s += sP[al][k] * W1[k * 64 + c];
        r += sP[al][k] * res0_w[k * 64 + c];
    }
    acc_out[a * 64 + c] = r;
    sH[al][c] = tanh_fast(s);
    __syncthreads();
    float s2 = b2[c];
#pragma unroll
    for (int k = 0; k < 64; ++k) s2 += sH[al][k] * W2[k * 64 + c];
    h_out[a * 64 + c] = (_Float16)tanh_fast(s2);
}

// ---------------- fused: output head depth d + atom MLP depth d+1
template <bool DO_ATOM>
__global__ __launch_bounds__(256)
void out_atom_kernel(const float* __restrict__ p_in,
                     const float* __restrict__ oW1, const float* __restrict__ ob1,
                     const float* __restrict__ oW2, const float* __restrict__ ob2,
                     const float* __restrict__ wo, float* __restrict__ out, int store,
                     const float* __restrict__ aW1, const float* __restrict__ ab1,
                     const float* __restrict__ aW2, const float* __restrict__ ab2,
                     _Float16* __restrict__ h_out, float* __restrict__ acc_next) {
    __shared__ float sP[4][64];
    __shared__ float sH[4][64];
    __shared__ float sH2[4][64];
    int tid = threadIdx.x;
    int al = tid >> 6, c = tid & 63;
    int a = blockIdx.x * 4 + al;
    float pv = p_in[a * 64 + c];
    sP[al][c] = pv;
    __syncthreads();
    float s1 = ob1[c];
    float s2 = DO_ATOM ? ab1[c] : 0.f;
#pragma unroll
    for (int k = 0; k < 64; ++k) {
        float p = sP[al][k];
        s1 += p * oW1[k * 64 + c];
        if (DO_ATOM) s2 += p * aW1[k * 64 + c];
    }
    sH[al][c] = tanh_fast(s1);
    if (DO_ATOM) sH2[al][c] = tanh_fast(s2);
    __syncthreads();
    float t1 = ob2[c];
    float t2 = DO_ATOM ? ab2[c] : 0.f;
#pragma unroll
    for (int k = 0; k < 64; ++k) {
        t1 += sH[al][k] * oW2[k * 64 + c];
        if (DO_ATOM) t2 += sH2[al][k] * aW2[k * 64 + c];
    }
    if (DO_ATOM) {
        h_out[a * 64 + c] = (_Float16)tanh_fast(t2);
        acc_next[a * 64 + c] = pv;
    }
    float v = tanh_fast(t1) * wo[c];
#pragma unroll
    for (int off = 32; off > 0; off >>= 1) v += __shfl_down(v, off, 64);
    if (c == 0) {
        if (store) out[a] = v;
        else out[a] += v;
    }
}

// ---------------- pair pipeline: atom-partitioned blocks, LDS segment accumulation,
// zero global atomics. LDS: sR 32K + sW2 32K + sAcc 12.25K = 76.25K -> 2 blocks/CU.
#define MFMA __builtin_amdgcn_mfma_f32_32x32x16_f16

__global__ __launch_bounds__(512, 4)
void pair_kernel(const _Float16* __restrict__ hh,
                 const int* __restrict__ ind2s,
                 const float* __restrict__ basisp,
                 const int* __restrict__ offs,       // post-scatter: offs[a] = end of atom a
                 const _Float16* __restrict__ img1,
                 const _Float16* __restrict__ img2,
                 const _Float16* __restrict__ imgab,
                 const float* __restrict__ piB1,
                 const float* __restrict__ b2p,
                 float* __restrict__ accp) {
    __shared__ __attribute__((aligned(16))) _Float16 sR[16384];  // A-frags; [0:8K]=X2, [8K:16K]=X1/X3
    __shared__ __attribute__((aligned(16))) _Float16 sW2[16384]; // 32 KB
    __shared__ float sAcc[APB * 64];                             // 12.25 KB segment accumulator

    const int tid = threadIdx.x;
    for (int i = tid; i < 2048; i += 512) ((uint4*)sW2)[i] = ((const uint4*)img2)[i];
    for (int i = tid; i < APB * 64; i += 512) sAcc[i] = 0.f;

    const int aLo = blockIdx.x * APB;
    const int aHi = min(aLo + APB, N_ATOMS);
    const int pStart = aLo ? offs[aLo - 1] : 0;
    const int pEnd = offs[aHi - 1];
    const int nT = (pEnd - pStart + 127) >> 7;

    const int l = tid & 63;
    const int w = tid >> 6;
    const int mt = w >> 1, ntw = w & 1;
    const int col = l & 31, kg = l >> 5;
    const int ch = ntw * 32 + col;
    const int chks = ch >> 4, chlh = (ch >> 3) & 1, chj = ch & 7;
    const int rr2 = (chks * 2 + chlh) ^ (kg << 2);
    const int cbase = (mt * 4 + chks) * 512 + chlh * 256 + (rr2 << 3) + chj;
    const int abase = kg * 256 + ((col ^ kg) << 3);

    f16x8 w1h[8], fa[4], fb[4];
#pragma unroll
    for (int ks = 0; ks < 8; ++ks)
        w1h[ks] = *(const f16x8*)(img1 + ntw * 4096 + ks * 512 + l * 8);
#pragma unroll
    for (int ks = 0; ks < 4; ++ks) {
        fa[ks] = *(const f16x8*)(imgab + ntw * 2048 + ks * 512 + l * 8);
        fb[ks] = *(const f16x8*)(imgab + 4096 + ntw * 2048 + ks * 512 + l * 8);
    }
    const float b1v = piB1[ch];
    float b2v[4];
#pragma unroll
    for (int t = 0; t < 4; ++t) b2v[t] = b2p[ntw * 128 + t * 32 + col];

    auto gather_now = [&](int tile) {
        int base = pStart + (tile << 7);
#pragma unroll
        for (int it = 0; it < 4; ++it) {
            int id = it * 512 + tid;
            int m = id >> 4, half = (id >> 3) & 1, seg = id & 7;
            int p = min(base + m, N_PAIRS - 1);
            int row = ind2s[2 * p + half];
            uint4 v = *(const uint4*)(hh + row * 64 + seg * 8);
            int ks = half * 4 + (seg >> 1), lh = seg & 1;
            *(uint4*)(sR + (((m >> 5) * 8 + ks) * 512 + lh * 256 +
                            (((m & 31) ^ (ks * 2 + lh)) << 3))) = v;
        }
    };
    if (nT > 0) gather_now(0);
    __syncthreads();   // covers sAcc zero, sW2 load, first gather

    for (int tile = 0; tile < nT; ++tile) {
        const int base = pStart + (tile << 7);

        // ---- G1: [128x128]@W1(regs)+b1, tanh
        f32x16 acc1 = {};
#pragma unroll
        for (int ks = 0; ks < 8; ++ks) {
            f16x8 a = *(const f16x8*)(sR + (mt * 8 + ks) * 512 + kg * 256 +
                                      ((col ^ (ks * 2 + kg)) << 3));
            acc1 = MFMA(a, w1h[ks], acc1, 0, 0, 0);
        }
        __syncthreads();   // B1: all A-frag reads done before X1 overwrites sR[8K:16K]
#pragma unroll
        for (int r = 0; r < 16; ++r) {
            const int Lc = (r & 3) + 8 * (r >> 2);
            sR[8192 + (cbase ^ (Lc << 3))] = (_Float16)tanh_fast(acc1[r] + b1v);
        }
        __syncthreads();   // B2: X1 visible

        // ---- G2: @W2(LDS)+b2, tanh, basis contraction -> X2 in sR[0:8K]
        {
            float inter[16];
#pragma unroll
            for (int r = 0; r < 16; ++r) inter[r] = 0.f;
#pragma unroll
            for (int t = 0; t < 4; ++t) {
                f32x16 acc = {};
#pragma unroll
                for (int ks = 0; ks < 4; ++ks) {
                    f16x8 a = *(const f16x8*)(sR + 8192 + (mt * 4 + ks) * 512 + (abase ^ (ks << 4)));
                    f16x8 b = *(const f16x8*)(sW2 + ((ntw * 4 + t) * 4 + ks) * 512 + l * 8);
                    acc = MFMA(a, b, acc, 0, 0, 0);
                }
#pragma unroll
                for (int r = 0; r < 16; ++r) {
                    const int Lc = (r & 3) + 8 * (r >> 2);
                    int p = min(base + mt * 32 + Lc + 4 * kg, N_PAIRS - 1);
                    float bs = basisp[4 * p + t];
                    inter[r] += tanh_fast(acc[r] + b2v[t]) * bs;
                }
            }
#pragma unroll
            for (int r = 0; r < 16; ++r) {
                const int Lc = (r & 3) + 8 * (r >> 2);
                sR[cbase ^ (Lc << 3)] = (_Float16)inter[r];   // X2 -> sR[0:8K] (disjoint from X1 reads)
            }
        }
        __syncthreads();   // B3

        // ---- G3: X2 @ ii_w1(regs), tanh -> X3 in sR[8K:16K] (X1 dead)
        {
            f32x16 acc = {};
#pragma unroll
            for (int ks = 0; ks < 4; ++ks) {
                f16x8 a = *(const f16x8*)(sR + (mt * 4 + ks) * 512 + (abase ^ (ks << 4)));
                acc = MFMA(a, fa[ks], acc, 0, 0, 0);
            }
#pragma unroll
            for (int r = 0; r < 16; ++r) {
                const int Lc = (r & 3) + 8 * (r >> 2);
                sR[8192 + (cbase ^ (Lc << 3))] = (_Float16)tanh_fast(acc[r]);
            }
        }
        __syncthreads();   // B4

        // ---- G4: read X3 -> regs; gather(next) loads; MFMA; LDS-atomic accumulate
        {
            f16x8 x3[4];
#pragma unroll
            for (int ks = 0; ks < 4; ++ks)
                x3[ks] = *(const f16x8*)(sR + 8192 + (mt * 4 + ks) * 512 + (abase ^ (ks << 4)));

            uint4 gv[4];
            int gaddr[4];
            int gbase = pStart + ((tile + 1) << 7);
#pragma unroll
            for (int it = 0; it < 4; ++it) {
                int id = it * 512 + tid;
                int m = id >> 4, half = (id >> 3) & 1, seg = id & 7;
                int p = min(gbase + m, N_PAIRS - 1);
                int row = ind2s[2 * p + half];
                gv[it] = *(const uint4*)(hh + row * 64 + seg * 8);
                int ks = half * 4 + (seg >> 1), lh = seg & 1;
                gaddr[it] = ((m >> 5) * 8 + ks) * 512 + lh * 256 +
                            (((m & 31) ^ (ks * 2 + lh)) << 3);
            }
            __syncthreads();   // B5: all X3 reads done before gather ds_writes

            f32x16 acc = {};
#pragma unroll
            for (int ks = 0; ks < 4; ++ks) acc = MFMA(x3[ks], fb[ks], acc, 0, 0, 0);

            // quad-merged LDS-atomic accumulation into block-local segment sums
#pragma unroll
            for (int q = 0; q < 4; ++q) {
                int prevLa = -1;
                float vac = 0.f;
#pragma unroll
                for (int i2 = 0; i2 < 4; ++i2) {
                    int r = q * 4 + i2;
                    int p = base + mt * 32 + 8 * q + 4 * kg + i2;
                    if (p < pEnd) {
                        int la = ind2s[2 * p] - aLo;
                        float v = tanh_fast(acc[r]);
                        if (la != prevLa) {
                            if (prevLa >= 0) atomicAdd(&sAcc[prevLa * 64 + ch], vac);
                            prevLa = la;
                            vac = v;
                        } else {
                            vac += v;
                        }
                    }
                }
                if (prevLa >= 0) atomicAdd(&sAcc[prevLa * 64 + ch], vac);
            }
#pragma unroll
            for (int it = 0; it < 4; ++it) *(uint4*)(sR + gaddr[it]) = gv[it];
        }
        __syncthreads();   // B6 (loop end)
    }

    // flush: each atom owned by exactly this block -> plain read-add-write, coalesced
    for (int i = tid; i < (aHi - aLo) * 64; i += 512)
        accp[aLo * 64 + i] += sAcc[i];
}

extern "C" void kernel_launch(void* const* d_in, const int* in_sizes, int n_in,
                              void* d_out, int out_size, void* d_ws, size_t ws_size,
                              hipStream_t stream) {
    const int* ind2 = (const int*)d_in[0];
    const float* prop = (const float*)d_in[1];
    const float* basis = (const float*)d_in[2];
    const float* pp0_w1 = (const float*)d_in[3];
    const float* pp0_b1 = (const float*)d_in[4];
    const float* pp_w1 = (const float*)d_in[5];
    const float* pp_b1 = (const float*)d_in[6];
    const float* pp_w2 = (const float*)d_in[7];
    const float* pp_b2 = (const float*)d_in[8];
    const float* pi_w1 = (const float*)d_in[9];
    const float* pi_b1 = (const float*)d_in[10];
    const float* pi_w2 = (const float*)d_in[11];
    const float* pi_b2 = (const float*)d_in[12];
    const float* ii_w1 = (const float*)d_in[13];
    const float* ii_w2 = (const float*)d_in[14];
    const float* res0_w = (const float*)d_in[15];
    const float* out_w1 = (const float*)d_in[16];
    const float* out_b1 = (const float*)d_in[17];
    const float* out_w2 = (const float*)d_in[18];
    const float* out_b2 = (const float*)d_in[19];
    const float* out_wo = (const float*)d_in[20];
    float* out = (float*)d_out;

    float* B0 = (float*)d_ws;
    float* B1 = B0 + N_ATOMS * 64;
    _Float16* Hhi = (_Float16*)(B1 + N_ATOMS * 64);
    _Float16* img1 = Hhi + N_ATOMS * 64;
    _Float16* img2 = img1 + 4 * 8192;
    _Float16* imgab = img2 + 4 * 16384;
    float* b2p = (float*)(imgab + 4 * 8192);
    int* hist = (int*)(b2p + 4 * 256);
    int* offs = hist + N_ATOMS;
    int* ind2s = offs + N_ATOMS;
    float* basisp = (float*)(ind2s + 2 * N_PAIRS);
    float* pbuf[2] = {B0, B1};

    hipMemsetAsync(hist, 0, N_ATOMS * sizeof(int), stream);
    hist_kernel<<<(N_PAIRS + 255) / 256, 256, 0, stream>>>(ind2, hist);
    scan_kernel<<<1, 1024, 0, stream>>>(hist, offs);
    scatter_kernel<<<(N_PAIRS + 255) / 256, 256, 0, stream>>>(ind2, basis, offs, ind2s, basisp);
    prep_kernel<<<512, 256, 0, stream>>>(pi_w1, pi_w2, ii_w1, ii_w2, img1, img2, imgab);
    prep_b2<<<4, 256, 0, stream>>>(pi_b2, b2p);

    const int grid = (N_ATOMS + APB - 1) / APB;   // 511
    for (int d = 0; d < DEPTH; ++d) {
        float* acc = pbuf[d & 1];
        if (d == 0) {
            atom_mlp0<<<N_ATOMS / 4, 256, 0, stream>>>(
                prop, pp0_w1, pp0_b1, pp_w2, pp_b2, res0_w, Hhi, acc);
        }
        pair_kernel<<<grid, 512, 0, stream>>>(
            Hhi, ind2s, basisp, offs,
            img1 + d * 8192, img2 + d * 16384, imgab + d * 8192,
            pi_b1 + d * 64, b2p + d * 256, acc);
        if (d < DEPTH - 1) {
            float* accN = pbuf[(d + 1) & 1];
            out_atom_kernel<true><<<N_ATOMS / 4, 256, 0, stream>>>(
                acc, out_w1 + d * 4096, out_b1 + d * 64,
                out_w2 + d * 4096, out_b2 + d * 64, out_wo + d * 64,
                out, d == 0 ? 1 : 0,
                pp_w1 + d * 4096, pp_b1 + d * 64,
                pp_w2 + (d + 1) * 4096, pp_b2 + (d + 1) * 64,
                Hhi, accN);
        } else {
            out_atom_kernel<false><<<N_ATOMS / 4, 256, 0, stream>>>(
                acc, out_w1 + d * 4096, out_b1 + d * 64,
                out_w2 + d * 4096, out_b2 + d * 64, out_wo + d * 64,
                out, 0,
                nullptr, nullptr, nullptr, nullptr, nullptr, nullptr);
        }
    }
}